// Round 1
// baseline (960.050 us; speedup 1.0000x reference)
//
#include <hip/hip_runtime.h>
#include <hip/hip_bf16.h>
#include <math.h>

// Problem constants (B=64, S=512, D=256, L=3)
#define D_HID 256
#define N_B   64
#define S_LEN 512
#define N_L   3
#define M_ROWS (N_B * S_LEN)   // 32768 rows

typedef __bf16 bf16_t;
typedef __bf16 bf16x8 __attribute__((ext_vector_type(8)));
typedef __bf16 bf16x4 __attribute__((ext_vector_type(4)));
typedef float  f32x4  __attribute__((ext_vector_type(4)));

__device__ __forceinline__ f32x4 mfma16(bf16x8 a, bf16x8 b, f32x4 c) {
    return __builtin_amdgcn_mfma_f32_16x16x32_bf16(a, b, c, 0, 0, 0);
}

// ---------------------------------------------------------------------------
// Weight transpose + bf16 convert: w[l][k][n] (f32) -> wt[l][n][k] (bf16)
// Output-index coalesced; scattered reads served by L2.
// ---------------------------------------------------------------------------
__global__ __launch_bounds__(256) void transpose_w(const float* __restrict__ w,
                                                   bf16_t* __restrict__ wt) {
    int i = blockIdx.x * 256 + threadIdx.x;   // total = L*D*D = 196608
    int k = i & 255;
    int n = (i >> 8) & 255;
    int l = i >> 16;
    wt[i] = (bf16_t)w[((size_t)l << 16) + ((size_t)k << 8) + n];
}

// ---------------------------------------------------------------------------
// LayerNorm: H = LN(in)*g + b  (f32 out + bf16 copy). One wave per row.
// ---------------------------------------------------------------------------
__global__ __launch_bounds__(256) void ln_fwd(const float* __restrict__ in,
                                              const float* __restrict__ g,
                                              const float* __restrict__ b,
                                              float* __restrict__ H,
                                              bf16_t* __restrict__ Hb) {
    int row  = blockIdx.x * 4 + (threadIdx.x >> 6);
    int lane = threadIdx.x & 63;
    float4 x = ((const float4*)(in + (size_t)row * D_HID))[lane];
    float s  = x.x + x.y + x.z + x.w;
    float sq = x.x * x.x + x.y * x.y + x.z * x.z + x.w * x.w;
#pragma unroll
    for (int o = 1; o < 64; o <<= 1) { s += __shfl_xor(s, o); sq += __shfl_xor(sq, o); }
    float mean = s * (1.f / D_HID);
    float rstd = rsqrtf(sq * (1.f / D_HID) - mean * mean + 1e-5f);
    float4 gv = ((const float4*)g)[lane];
    float4 bv = ((const float4*)b)[lane];
    float4 h;
    h.x = (x.x - mean) * rstd * gv.x + bv.x;
    h.y = (x.y - mean) * rstd * gv.y + bv.y;
    h.z = (x.z - mean) * rstd * gv.z + bv.z;
    h.w = (x.w - mean) * rstd * gv.w + bv.w;
    ((float4*)(H + (size_t)row * D_HID))[lane] = h;
    bf16x4 hb = { (bf16_t)h.x, (bf16_t)h.y, (bf16_t)h.z, (bf16_t)h.w };
    *((bf16x4*)(Hb + (size_t)row * D_HID) + lane) = hb;
}

// ---------------------------------------------------------------------------
// Fused: X = H + LN(T)*g + b ; Cb = bf16( LN(X)*cg + cb ). One wave per row.
// ---------------------------------------------------------------------------
__global__ __launch_bounds__(256) void ln_res_ln(const float* __restrict__ T,
                                                 const float* __restrict__ H,
                                                 const float* __restrict__ g,
                                                 const float* __restrict__ b,
                                                 const float* __restrict__ cg,
                                                 const float* __restrict__ cb,
                                                 float* __restrict__ X,
                                                 bf16_t* __restrict__ Cb) {
    int row  = blockIdx.x * 4 + (threadIdx.x >> 6);
    int lane = threadIdx.x & 63;
    float4 t = ((const float4*)(T + (size_t)row * D_HID))[lane];
    float s  = t.x + t.y + t.z + t.w;
    float sq = t.x * t.x + t.y * t.y + t.z * t.z + t.w * t.w;
#pragma unroll
    for (int o = 1; o < 64; o <<= 1) { s += __shfl_xor(s, o); sq += __shfl_xor(sq, o); }
    float mean = s * (1.f / D_HID);
    float rstd = rsqrtf(sq * (1.f / D_HID) - mean * mean + 1e-5f);
    float4 gv = ((const float4*)g)[lane];
    float4 bv = ((const float4*)b)[lane];
    float4 hh = ((const float4*)(H + (size_t)row * D_HID))[lane];
    float4 x;
    x.x = hh.x + (t.x - mean) * rstd * gv.x + bv.x;
    x.y = hh.y + (t.y - mean) * rstd * gv.y + bv.y;
    x.z = hh.z + (t.z - mean) * rstd * gv.z + bv.z;
    x.w = hh.w + (t.w - mean) * rstd * gv.w + bv.w;
    ((float4*)(X + (size_t)row * D_HID))[lane] = x;
    // second LN
    float s2  = x.x + x.y + x.z + x.w;
    float sq2 = x.x * x.x + x.y * x.y + x.z * x.z + x.w * x.w;
#pragma unroll
    for (int o = 1; o < 64; o <<= 1) { s2 += __shfl_xor(s2, o); sq2 += __shfl_xor(sq2, o); }
    float mean2 = s2 * (1.f / D_HID);
    float rstd2 = rsqrtf(sq2 * (1.f / D_HID) - mean2 * mean2 + 1e-5f);
    float4 cgv = ((const float4*)cg)[lane];
    float4 cbv = ((const float4*)cb)[lane];
    bf16x4 c = { (bf16_t)((x.x - mean2) * rstd2 * cgv.x + cbv.x),
                 (bf16_t)((x.y - mean2) * rstd2 * cgv.y + cbv.y),
                 (bf16_t)((x.z - mean2) * rstd2 * cgv.z + cbv.z),
                 (bf16_t)((x.w - mean2) * rstd2 * cgv.w + cbv.w) };
    *((bf16x4*)(Cb + (size_t)row * D_HID) + lane) = c;
}

// ---------------------------------------------------------------------------
// GEMM: C[M,256] = A[M,256](bf16) @ Wt[256,256]^T(bf16) + bias, epilogues:
//   EPI 0: store bf16   1: gelu->bf16   2: store f32   3: addsrc + -> f32
// Block: 256 thr = 4 waves (2x2), tile 128x64, K-loop 8x32, MFMA 16x16x32.
// ---------------------------------------------------------------------------
template <int EPI>
__global__ __launch_bounds__(256) void gemm256(const bf16_t* __restrict__ A,
                                               const bf16_t* __restrict__ Wt,
                                               const float* __restrict__ bias,
                                               void* __restrict__ outp,
                                               const float* __restrict__ addsrc) {
    const int lane = threadIdx.x & 63;
    const int wid  = threadIdx.x >> 6;
    const int wm = wid >> 1, wn = wid & 1;
    const int m0 = blockIdx.x * 128 + wm * 64;
    const int n0 = blockIdx.y * 64 + wn * 32;
    const int r = lane & 15, g = lane >> 4;
    f32x4 acc[4][2] = {};
#pragma unroll
    for (int ks = 0; ks < 8; ++ks) {
        const int kb = ks * 32 + g * 8;
        bf16x8 a[4], bb[2];
#pragma unroll
        for (int mt = 0; mt < 4; ++mt)
            a[mt] = *(const bf16x8*)(A + (size_t)(m0 + mt * 16 + r) * D_HID + kb);
#pragma unroll
        for (int nt = 0; nt < 2; ++nt)
            bb[nt] = *(const bf16x8*)(Wt + (size_t)(n0 + nt * 16 + r) * D_HID + kb);
#pragma unroll
        for (int mt = 0; mt < 4; ++mt)
#pragma unroll
            for (int nt = 0; nt < 2; ++nt)
                acc[mt][nt] = mfma16(a[mt], bb[nt], acc[mt][nt]);
    }
#pragma unroll
    for (int nt = 0; nt < 2; ++nt) {
        const int col = n0 + nt * 16 + r;
        const float bv = bias[col];
#pragma unroll
        for (int mt = 0; mt < 4; ++mt) {
#pragma unroll
            for (int rr = 0; rr < 4; ++rr) {
                const size_t idx = (size_t)(m0 + mt * 16 + g * 4 + rr) * D_HID + col;
                float v = acc[mt][nt][rr] + bv;
                if constexpr (EPI == 0) {
                    ((bf16_t*)outp)[idx] = (bf16_t)v;
                } else if constexpr (EPI == 1) {
                    v = 0.5f * v * (1.f + erff(v * 0.70710678118654752f));
                    ((bf16_t*)outp)[idx] = (bf16_t)v;
                } else if constexpr (EPI == 2) {
                    ((float*)outp)[idx] = v;
                } else {
                    ((float*)outp)[idx] = addsrc[idx] + v;
                }
            }
        }
    }
}

// ---------------------------------------------------------------------------
// Flash attention. Grid (B, S/32). 4 waves. Per k-tile of 64 keys:
//  ph1: MFMA QK^T -> LDS scores; ph2: online softmax (8 lanes/row) -> P bf16;
//  ph3: rescale O-acc, MFMA P@V (V gathered from global, L2-resident).
// ---------------------------------------------------------------------------
__global__ __launch_bounds__(256) void attn_fwd(const bf16_t* __restrict__ Q,
                                                const bf16_t* __restrict__ K,
                                                const bf16_t* __restrict__ V,
                                                const float* __restrict__ btab,
                                                const int* __restrict__ mask,
                                                bf16_t* __restrict__ AO) {
    const int b  = blockIdx.x;
    const int q0 = blockIdx.y * 32;
    const int tid  = threadIdx.x;
    const int lane = tid & 63;
    const int w    = tid >> 6;
    const int r = lane & 15, g = lane >> 4;

    __shared__ float  s_tile[32][65];   // padded: kills 4-way write conflicts
    __shared__ bf16_t p_tile[32][72];   // padded: row stride 144B
    __shared__ float  m_s[32], l_s[32], fac_s[32];
    if (tid < 32) { m_s[tid] = -3.0e38f; l_s[tid] = 0.f; }

    const bf16_t* Qp = Q + ((size_t)b * S_LEN + q0) * D_HID;
    const bf16_t* Kp = K + (size_t)b * S_LEN * D_HID;
    const bf16_t* Vp = V + (size_t)b * S_LEN * D_HID;

    f32x4 oacc[2][4] = {};   // m-tiles(2) x d-tiles(4): wave owns d = w*64..w*64+63

    for (int kt = 0; kt < 8; ++kt) {
        const int k0 = kt * 64;
        // ---- ph1: scores for 16 keys per wave (keys k0 + w*16 + r)
        f32x4 sacc0 = {0.f, 0.f, 0.f, 0.f}, sacc1 = {0.f, 0.f, 0.f, 0.f};
#pragma unroll
        for (int ks = 0; ks < 8; ++ks) {
            const int kb = ks * 32 + g * 8;
            bf16x8 aq0 = *(const bf16x8*)(Qp + (size_t)r * D_HID + kb);
            bf16x8 aq1 = *(const bf16x8*)(Qp + (size_t)(16 + r) * D_HID + kb);
            bf16x8 bk  = *(const bf16x8*)(Kp + (size_t)(k0 + w * 16 + r) * D_HID + kb);
            sacc0 = mfma16(aq0, bk, sacc0);
            sacc1 = mfma16(aq1, bk, sacc1);
        }
#pragma unroll
        for (int rr = 0; rr < 4; ++rr) {
            s_tile[g * 4 + rr][w * 16 + r]      = sacc0[rr];
            s_tile[16 + g * 4 + rr][w * 16 + r] = sacc1[rr];
        }
        __syncthreads();
        // ---- ph2: online softmax over this 64-key tile (8 threads per q-row)
        {
            const int q  = tid >> 3;
            const int kc = (tid & 7) * 8;
            const int qg = q0 + q;
            float e[8];
#pragma unroll
            for (int i = 0; i < 8; ++i) {
                const int kk = k0 + kc + i;
                const int rel = kk - qg;
                const int bucket = (rel < 0) ? (511 - rel) : rel;
                float ev = s_tile[q][kc + i] * 0.0625f + btab[bucket];
                if (mask[b * S_LEN + kk] == 0) ev = -3.0e38f;
                e[i] = ev;
            }
            float mx = e[0];
#pragma unroll
            for (int i = 1; i < 8; ++i) mx = fmaxf(mx, e[i]);
            mx = fmaxf(mx, __shfl_xor(mx, 1));
            mx = fmaxf(mx, __shfl_xor(mx, 2));
            mx = fmaxf(mx, __shfl_xor(mx, 4));
            const float m_old = m_s[q];
            const float m_new = fmaxf(m_old, mx);
            float p[8], ps = 0.f;
#pragma unroll
            for (int i = 0; i < 8; ++i) { p[i] = __expf(e[i] - m_new); ps += p[i]; }
            ps += __shfl_xor(ps, 1);
            ps += __shfl_xor(ps, 2);
            ps += __shfl_xor(ps, 4);
            if ((tid & 7) == 0) {
                const float f = __expf(m_old - m_new);
                fac_s[q] = f;
                l_s[q]   = l_s[q] * f + ps;
                m_s[q]   = m_new;
            }
            bf16x8 pb;
#pragma unroll
            for (int i = 0; i < 8; ++i) pb[i] = (bf16_t)p[i];
            *(bf16x8*)(&p_tile[q][kc]) = pb;
        }
        __syncthreads();
        // ---- ph3: rescale accumulator + P@V
        float fr0[4], fr1[4];
#pragma unroll
        for (int rr = 0; rr < 4; ++rr) {
            fr0[rr] = fac_s[g * 4 + rr];
            fr1[rr] = fac_s[16 + g * 4 + rr];
        }
#pragma unroll
        for (int nt = 0; nt < 4; ++nt)
#pragma unroll
            for (int rr = 0; rr < 4; ++rr) {
                oacc[0][nt][rr] *= fr0[rr];
                oacc[1][nt][rr] *= fr1[rr];
            }
#pragma unroll
        for (int ks = 0; ks < 2; ++ks) {
            bf16x8 pa0 = *(const bf16x8*)(&p_tile[r][ks * 32 + g * 8]);
            bf16x8 pa1 = *(const bf16x8*)(&p_tile[16 + r][ks * 32 + g * 8]);
#pragma unroll
            for (int nt = 0; nt < 4; ++nt) {
                bf16x8 vb;
#pragma unroll
                for (int j = 0; j < 8; ++j)
                    vb[j] = Vp[(size_t)(k0 + ks * 32 + g * 8 + j) * D_HID + w * 64 + nt * 16 + r];
                oacc[0][nt] = mfma16(pa0, vb, oacc[0][nt]);
                oacc[1][nt] = mfma16(pa1, vb, oacc[1][nt]);
            }
        }
        __syncthreads();
    }
    // ---- finalize: divide by softmax denominator, store bf16
    float li0[4], li1[4];
#pragma unroll
    for (int rr = 0; rr < 4; ++rr) {
        li0[rr] = 1.f / l_s[g * 4 + rr];
        li1[rr] = 1.f / l_s[16 + g * 4 + rr];
    }
    bf16_t* Op = AO + ((size_t)b * S_LEN + q0) * D_HID;
#pragma unroll
    for (int nt = 0; nt < 4; ++nt)
#pragma unroll
        for (int rr = 0; rr < 4; ++rr) {
            Op[(size_t)(g * 4 + rr) * D_HID + w * 64 + nt * 16 + r]      = (bf16_t)(oacc[0][nt][rr] * li0[rr]);
            Op[(size_t)(16 + g * 4 + rr) * D_HID + w * 64 + nt * 16 + r] = (bf16_t)(oacc[1][nt][rr] * li1[rr]);
        }
}

// ---------------------------------------------------------------------------
extern "C" void kernel_launch(void* const* d_in, const int* in_sizes, int n_in,
                              void* d_out, int out_size, void* d_ws, size_t ws_size,
                              hipStream_t stream) {
    const float* x_in = (const float*)d_in[0];
    const int*   mask = (const int*)d_in[1];
    const float* btab = (const float*)d_in[2];
    const float* ln_g = (const float*)d_in[3];
    const float* ln_b = (const float*)d_in[4];
    const float* wq = (const float*)d_in[5];
    const float* bq = (const float*)d_in[6];
    const float* wk = (const float*)d_in[7];
    const float* bk = (const float*)d_in[8];
    const float* wv = (const float*)d_in[9];
    const float* bv = (const float*)d_in[10];
    const float* wo = (const float*)d_in[11];
    const float* bo = (const float*)d_in[12];
    const float* cg = (const float*)d_in[13];
    const float* cb = (const float*)d_in[14];
    const float* w1 = (const float*)d_in[15];
    const float* b1 = (const float*)d_in[16];
    const float* w2 = (const float*)d_in[17];
    const float* b2 = (const float*)d_in[18];
    float* out = (float*)d_out;

    // Workspace layout (~137 MB), regions reused across stage lifetimes.
    char* p = (char*)d_ws;
    const size_t F32SZ  = (size_t)M_ROWS * D_HID * sizeof(float);   // 33.5 MB
    const size_t BF16SZ = (size_t)M_ROWS * D_HID * sizeof(bf16_t);  // 16.8 MB
    float*  H  = (float*)p;  p += F32SZ;
    float*  X  = (float*)p;  p += F32SZ;
    bf16_t* Hb = (bf16_t*)p; p += BF16SZ;   // later: AO (attention output)
    bf16_t* Qb = (bf16_t*)p; p += BF16SZ;   // later: Cb (cm-LN output)
    bf16_t* Kb = (bf16_t*)p;                // region also holds T (f32) then T1b
    float*  T  = (float*)Kb;                // spans Kb+Vb (33.5 MB f32)
    bf16_t* T1b = Kb;
    p += BF16SZ;
    bf16_t* Vb = (bf16_t*)p; p += BF16SZ;
    bf16_t* Wt = (bf16_t*)p;                // 6 * L * 256*256 bf16 = 2.36 MB
    bf16_t* AO = Hb;
    bf16_t* Cb = Qb;

    const int WELEMS = N_L * D_HID * D_HID;   // 196608 per weight tensor
    const float* wsrc[6] = {wq, wk, wv, wo, w1, w2};
    for (int wdx = 0; wdx < 6; ++wdx)
        transpose_w<<<dim3(WELEMS / 256), dim3(256), 0, stream>>>(wsrc[wdx], Wt + (size_t)wdx * WELEMS);

    const dim3 gblk(256, 1, 1);
    const dim3 ggrid(M_ROWS / 128, D_HID / 64, 1);

    for (int j = 0; j < N_L; ++j) {
        const bf16_t* WQt = Wt + ((size_t)0 * N_L + j) * D_HID * D_HID;
        const bf16_t* WKt = Wt + ((size_t)1 * N_L + j) * D_HID * D_HID;
        const bf16_t* WVt = Wt + ((size_t)2 * N_L + j) * D_HID * D_HID;
        const bf16_t* WOt = Wt + ((size_t)3 * N_L + j) * D_HID * D_HID;
        const bf16_t* W1t = Wt + ((size_t)4 * N_L + j) * D_HID * D_HID;
        const bf16_t* W2t = Wt + ((size_t)5 * N_L + j) * D_HID * D_HID;

        ln_fwd<<<dim3(M_ROWS / 4), gblk, 0, stream>>>(j == 0 ? x_in : X,
                                                      ln_g + j * D_HID, ln_b + j * D_HID, H, Hb);
        gemm256<0><<<ggrid, gblk, 0, stream>>>(Hb, WQt, bq + j * D_HID, Qb, nullptr);
        gemm256<0><<<ggrid, gblk, 0, stream>>>(Hb, WKt, bk + j * D_HID, Kb, nullptr);
        gemm256<0><<<ggrid, gblk, 0, stream>>>(Hb, WVt, bv + j * D_HID, Vb, nullptr);
        attn_fwd<<<dim3(N_B, S_LEN / 32), gblk, 0, stream>>>(Qb, Kb, Vb, btab, mask, AO);
        gemm256<2><<<ggrid, gblk, 0, stream>>>(AO, WOt, bo + j * D_HID, T, nullptr);
        ln_res_ln<<<dim3(M_ROWS / 4), gblk, 0, stream>>>(T, H, ln_g + j * D_HID, ln_b + j * D_HID,
                                                         cg + j * D_HID, cb + j * D_HID, X, Cb);
        gemm256<1><<<ggrid, gblk, 0, stream>>>(Cb, W1t, b1 + j * D_HID, T1b, nullptr);
        gemm256<3><<<ggrid, gblk, 0, stream>>>(T1b, W2t, b2 + j * D_HID,
                                               (j == N_L - 1) ? (void*)out : (void*)X, X);
    }
}

// Round 2
// 788.623 us; speedup vs baseline: 1.2174x; 1.2174x over previous
//
#include <hip/hip_runtime.h>
#include <hip/hip_bf16.h>
#include <math.h>

// Problem constants (B=64, S=512, D=256, L=3)
#define D_HID 256
#define N_B   64
#define S_LEN 512
#define N_L   3
#define M_ROWS (N_B * S_LEN)   // 32768 rows

typedef __bf16 bf16_t;
typedef __bf16 bf16x8 __attribute__((ext_vector_type(8)));
typedef __bf16 bf16x4 __attribute__((ext_vector_type(4)));
typedef float  f32x4  __attribute__((ext_vector_type(4)));
typedef unsigned int u32;

__device__ __forceinline__ f32x4 mfma16(bf16x8 a, bf16x8 b, f32x4 c) {
    return __builtin_amdgcn_mfma_f32_16x16x32_bf16(a, b, c, 0, 0, 0);
}

// async global->LDS, 16B per lane; LDS dest = wave-uniform base + lane*16
__device__ __forceinline__ void gld_lds16(const void* g, void* l) {
    __builtin_amdgcn_global_load_lds((const __attribute__((address_space(1))) u32*)g,
                                     (__attribute__((address_space(3))) u32*)l, 16, 0, 0);
}

// ---------------------------------------------------------------------------
// Weight transpose + bf16 convert: w[l][k][n] (f32) -> wt[l*ls + n*256 + k]
// ---------------------------------------------------------------------------
__global__ __launch_bounds__(256) void transpose_w(const float* __restrict__ w,
                                                   bf16_t* __restrict__ wt,
                                                   int layer_stride) {
    int i = blockIdx.x * 256 + threadIdx.x;   // total = L*D*D = 196608
    int k = i & 255;
    int n = (i >> 8) & 255;
    int l = i >> 16;
    wt[(size_t)l * layer_stride + n * 256 + k] =
        (bf16_t)w[((size_t)l << 16) + ((size_t)k << 8) + n];
}

// ---------------------------------------------------------------------------
// LayerNorm: H = LN(in)*g + b  (f32 out + bf16 copy). One wave per row.
// ---------------------------------------------------------------------------
__global__ __launch_bounds__(256) void ln_fwd(const float* __restrict__ in,
                                              const float* __restrict__ g,
                                              const float* __restrict__ b,
                                              float* __restrict__ H,
                                              bf16_t* __restrict__ Hb) {
    int row  = blockIdx.x * 4 + (threadIdx.x >> 6);
    int lane = threadIdx.x & 63;
    float4 x = ((const float4*)(in + (size_t)row * D_HID))[lane];
    float s  = x.x + x.y + x.z + x.w;
    float sq = x.x * x.x + x.y * x.y + x.z * x.z + x.w * x.w;
#pragma unroll
    for (int o = 1; o < 64; o <<= 1) { s += __shfl_xor(s, o); sq += __shfl_xor(sq, o); }
    float mean = s * (1.f / D_HID);
    float rstd = rsqrtf(sq * (1.f / D_HID) - mean * mean + 1e-5f);
    float4 gv = ((const float4*)g)[lane];
    float4 bv = ((const float4*)b)[lane];
    float4 h;
    h.x = (x.x - mean) * rstd * gv.x + bv.x;
    h.y = (x.y - mean) * rstd * gv.y + bv.y;
    h.z = (x.z - mean) * rstd * gv.z + bv.z;
    h.w = (x.w - mean) * rstd * gv.w + bv.w;
    ((float4*)(H + (size_t)row * D_HID))[lane] = h;
    bf16x4 hb = { (bf16_t)h.x, (bf16_t)h.y, (bf16_t)h.z, (bf16_t)h.w };
    *((bf16x4*)(Hb + (size_t)row * D_HID) + lane) = hb;
}

// ---------------------------------------------------------------------------
// Fused: X = H + LN(T)*g + b ; Cb = bf16( LN(X)*cg + cb ). One wave per row.
// ---------------------------------------------------------------------------
__global__ __launch_bounds__(256) void ln_res_ln(const float* __restrict__ T,
                                                 const float* __restrict__ H,
                                                 const float* __restrict__ g,
                                                 const float* __restrict__ b,
                                                 const float* __restrict__ cg,
                                                 const float* __restrict__ cb,
                                                 float* __restrict__ X,
                                                 bf16_t* __restrict__ Cb) {
    int row  = blockIdx.x * 4 + (threadIdx.x >> 6);
    int lane = threadIdx.x & 63;
    float4 t = ((const float4*)(T + (size_t)row * D_HID))[lane];
    float s  = t.x + t.y + t.z + t.w;
    float sq = t.x * t.x + t.y * t.y + t.z * t.z + t.w * t.w;
#pragma unroll
    for (int o = 1; o < 64; o <<= 1) { s += __shfl_xor(s, o); sq += __shfl_xor(sq, o); }
    float mean = s * (1.f / D_HID);
    float rstd = rsqrtf(sq * (1.f / D_HID) - mean * mean + 1e-5f);
    float4 gv = ((const float4*)g)[lane];
    float4 bv = ((const float4*)b)[lane];
    float4 hh = ((const float4*)(H + (size_t)row * D_HID))[lane];
    float4 x;
    x.x = hh.x + (t.x - mean) * rstd * gv.x + bv.x;
    x.y = hh.y + (t.y - mean) * rstd * gv.y + bv.y;
    x.z = hh.z + (t.z - mean) * rstd * gv.z + bv.z;
    x.w = hh.w + (t.w - mean) * rstd * gv.w + bv.w;
    ((float4*)(X + (size_t)row * D_HID))[lane] = x;
    // second LN
    float s2  = x.x + x.y + x.z + x.w;
    float sq2 = x.x * x.x + x.y * x.y + x.z * x.z + x.w * x.w;
#pragma unroll
    for (int o = 1; o < 64; o <<= 1) { s2 += __shfl_xor(s2, o); sq2 += __shfl_xor(sq2, o); }
    float mean2 = s2 * (1.f / D_HID);
    float rstd2 = rsqrtf(sq2 * (1.f / D_HID) - mean2 * mean2 + 1e-5f);
    float4 cgv = ((const float4*)cg)[lane];
    float4 cbv = ((const float4*)cb)[lane];
    bf16x4 c = { (bf16_t)((x.x - mean2) * rstd2 * cgv.x + cbv.x),
                 (bf16_t)((x.y - mean2) * rstd2 * cgv.y + cbv.y),
                 (bf16_t)((x.z - mean2) * rstd2 * cgv.z + cbv.z),
                 (bf16_t)((x.w - mean2) * rstd2 * cgv.w + cbv.w) };
    *((bf16x4*)(Cb + (size_t)row * D_HID) + lane) = c;
}

// ---------------------------------------------------------------------------
// GEMM core: 128x128 tile, BK=64, LDS-staged (global_load_lds w=16), XOR
// swizzle per rule #21: linear LDS dest + inverse-permuted global source +
// XOR on ds_read. 4 waves (2x2), wave = 64x64 out, acc[4][4] f32x4.
// ---------------------------------------------------------------------------
__device__ __forceinline__ void gemm_core(const bf16_t* __restrict__ A,
                                          const bf16_t* __restrict__ W,
                                          int m0, int n0,
                                          bf16_t* As, bf16_t* Bs,
                                          f32x4 (&acc)[4][4]) {
    const int tid  = threadIdx.x;
    const int lane = tid & 63;
    const int wid  = tid >> 6;
    const int wm = wid >> 1, wn = wid & 1;
    const int r = lane & 15, g = lane >> 4;
#pragma unroll 1
    for (int kt = 0; kt < 4; ++kt) {
        if (kt) __syncthreads();
#pragma unroll
        for (int i = 0; i < 4; ++i) {
            const int base8 = i * 256 + wid * 64;          // wave-uniform
            const int idx8  = base8 + lane;
            const int row   = idx8 >> 3;
            const int sc8   = (idx8 & 7) ^ (row & 7);      // inverse swizzle on SRC
            gld_lds16(A + (size_t)(m0 + row) * D_HID + kt * 64 + sc8 * 8, As + base8 * 8);
            gld_lds16(W + (size_t)(n0 + row) * D_HID + kt * 64 + sc8 * 8, Bs + base8 * 8);
        }
        __syncthreads();
#pragma unroll
        for (int ks = 0; ks < 2; ++ks) {
            bf16x8 af[4], bfr[4];
#pragma unroll
            for (int mt = 0; mt < 4; ++mt) {
                const int row = wm * 64 + mt * 16 + r;
                const int c8  = (ks * 4 + g) ^ (row & 7);  // swizzle on READ
                af[mt] = *(const bf16x8*)(As + row * 64 + c8 * 8);
            }
#pragma unroll
            for (int nt = 0; nt < 4; ++nt) {
                const int row = wn * 64 + nt * 16 + r;
                const int c8  = (ks * 4 + g) ^ (row & 7);
                bfr[nt] = *(const bf16x8*)(Bs + row * 64 + c8 * 8);
            }
#pragma unroll
            for (int mt = 0; mt < 4; ++mt)
#pragma unroll
                for (int nt = 0; nt < 4; ++nt)
                    acc[mt][nt] = mfma16(af[mt], bfr[nt], acc[mt][nt]);
        }
    }
}

// Fused QKV GEMM: Wp packed [768][256], cols 0-255->Qb, 256-511->Kb,
// 512-767 -> Vt (transposed [b][d][s]). Grid (M/128, 6).
__global__ __launch_bounds__(256) void gemm_qkv(const bf16_t* __restrict__ A,
                                                const bf16_t* __restrict__ Wp,
                                                const float* __restrict__ bq,
                                                const float* __restrict__ bk,
                                                const float* __restrict__ bv,
                                                bf16_t* __restrict__ Qb,
                                                bf16_t* __restrict__ Kb,
                                                bf16_t* __restrict__ Vt) {
    __shared__ bf16_t As[128 * 64], Bs[128 * 64];
    f32x4 acc[4][4] = {};
    const int m0 = blockIdx.x * 128, n0 = blockIdx.y * 128;
    gemm_core(A, Wp, m0, n0, As, Bs, acc);
    const int lane = threadIdx.x & 63, wid = threadIdx.x >> 6;
    const int wm = wid >> 1, wn = wid & 1, r = lane & 15, g = lane >> 4;
#pragma unroll
    for (int nt = 0; nt < 4; ++nt) {
        const int col = n0 + wn * 64 + nt * 16 + r;
        const int t = col >> 8, cc = col & 255;
        const float bias = (t == 0 ? bq : t == 1 ? bk : bv)[cc];
#pragma unroll
        for (int mt = 0; mt < 4; ++mt)
#pragma unroll
            for (int rr = 0; rr < 4; ++rr) {
                const int row = m0 + wm * 64 + mt * 16 + g * 4 + rr;
                const float v = acc[mt][nt][rr] + bias;
                if (t == 0)      Qb[(size_t)row * D_HID + cc] = (bf16_t)v;
                else if (t == 1) Kb[(size_t)row * D_HID + cc] = (bf16_t)v;
                else             Vt[((size_t)(row >> 9) * D_HID + cc) * S_LEN + (row & 511)] = (bf16_t)v;
            }
    }
}

// Generic GEMM, N=256. EPI 1: gelu->bf16  2: f32  3: addsrc+ -> f32
template <int EPI>
__global__ __launch_bounds__(256) void gemm_one(const bf16_t* __restrict__ A,
                                                const bf16_t* __restrict__ W,
                                                const float* __restrict__ bias,
                                                void* __restrict__ outp,
                                                const float* __restrict__ addsrc) {
    __shared__ bf16_t As[128 * 64], Bs[128 * 64];
    f32x4 acc[4][4] = {};
    const int m0 = blockIdx.x * 128, n0 = blockIdx.y * 128;
    gemm_core(A, W, m0, n0, As, Bs, acc);
    const int lane = threadIdx.x & 63, wid = threadIdx.x >> 6;
    const int wm = wid >> 1, wn = wid & 1, r = lane & 15, g = lane >> 4;
#pragma unroll
    for (int nt = 0; nt < 4; ++nt) {
        const int col = n0 + wn * 64 + nt * 16 + r;
        const float bv = bias[col];
#pragma unroll
        for (int mt = 0; mt < 4; ++mt)
#pragma unroll
            for (int rr = 0; rr < 4; ++rr) {
                const size_t idx = (size_t)(m0 + wm * 64 + mt * 16 + g * 4 + rr) * D_HID + col;
                float v = acc[mt][nt][rr] + bv;
                if constexpr (EPI == 1) {
                    v = 0.5f * v * (1.f + erff(v * 0.70710678118654752f));
                    ((bf16_t*)outp)[idx] = (bf16_t)v;
                } else if constexpr (EPI == 2) {
                    ((float*)outp)[idx] = v;
                } else {
                    ((float*)outp)[idx] = addsrc[idx] + v;
                }
            }
    }
}

// ---------------------------------------------------------------------------
// Flash attention. Grid (B, S/32). 4 waves. V read from transposed Vt[b][d][s]
// so P@V B-fragments are contiguous 16B loads (L2-resident).
// ---------------------------------------------------------------------------
__global__ __launch_bounds__(256) void attn_fwd(const bf16_t* __restrict__ Q,
                                                const bf16_t* __restrict__ K,
                                                const bf16_t* __restrict__ Vt,
                                                const float* __restrict__ btab,
                                                const int* __restrict__ mask,
                                                bf16_t* __restrict__ AO) {
    const int b  = blockIdx.x;
    const int q0 = blockIdx.y * 32;
    const int tid  = threadIdx.x;
    const int lane = tid & 63;
    const int w    = tid >> 6;
    const int r = lane & 15, g = lane >> 4;

    __shared__ float  s_tile[32][65];
    __shared__ bf16_t p_tile[32][72];
    __shared__ float  m_s[32], l_s[32], fac_s[32];
    if (tid < 32) { m_s[tid] = -3.0e38f; l_s[tid] = 0.f; }

    const bf16_t* Qp  = Q  + ((size_t)b * S_LEN + q0) * D_HID;
    const bf16_t* Kp  = K  + (size_t)b * S_LEN * D_HID;
    const bf16_t* Vtp = Vt + (size_t)b * D_HID * S_LEN;

    f32x4 oacc[2][4] = {};   // m-tiles(2) x d-tiles(4): wave owns d = w*64..w*64+63

    for (int kt = 0; kt < 8; ++kt) {
        const int k0 = kt * 64;
        // ---- ph1: scores for 16 keys per wave
        f32x4 sacc0 = {0.f, 0.f, 0.f, 0.f}, sacc1 = {0.f, 0.f, 0.f, 0.f};
#pragma unroll
        for (int ks = 0; ks < 8; ++ks) {
            const int kb = ks * 32 + g * 8;
            bf16x8 aq0 = *(const bf16x8*)(Qp + (size_t)r * D_HID + kb);
            bf16x8 aq1 = *(const bf16x8*)(Qp + (size_t)(16 + r) * D_HID + kb);
            bf16x8 bk  = *(const bf16x8*)(Kp + (size_t)(k0 + w * 16 + r) * D_HID + kb);
            sacc0 = mfma16(aq0, bk, sacc0);
            sacc1 = mfma16(aq1, bk, sacc1);
        }
#pragma unroll
        for (int rr = 0; rr < 4; ++rr) {
            s_tile[g * 4 + rr][w * 16 + r]      = sacc0[rr];
            s_tile[16 + g * 4 + rr][w * 16 + r] = sacc1[rr];
        }
        __syncthreads();
        // ---- ph2: online softmax over this 64-key tile (8 threads per q-row)
        {
            const int q  = tid >> 3;
            const int kc = (tid & 7) * 8;
            const int qg = q0 + q;
            const int4 mk0 = *(const int4*)(mask + b * S_LEN + k0 + kc);
            const int4 mk1 = *(const int4*)(mask + b * S_LEN + k0 + kc + 4);
            const int mk[8] = { mk0.x, mk0.y, mk0.z, mk0.w, mk1.x, mk1.y, mk1.z, mk1.w };
            float e[8];
#pragma unroll
            for (int i = 0; i < 8; ++i) {
                const int kk = k0 + kc + i;
                const int rel = kk - qg;
                const int bucket = (rel < 0) ? (511 - rel) : rel;
                float ev = s_tile[q][kc + i] * 0.0625f + btab[bucket];
                if (mk[i] == 0) ev = -3.0e38f;
                e[i] = ev;
            }
            float mx = e[0];
#pragma unroll
            for (int i = 1; i < 8; ++i) mx = fmaxf(mx, e[i]);
            mx = fmaxf(mx, __shfl_xor(mx, 1));
            mx = fmaxf(mx, __shfl_xor(mx, 2));
            mx = fmaxf(mx, __shfl_xor(mx, 4));
            const float m_old = m_s[q];
            const float m_new = fmaxf(m_old, mx);
            float p[8], ps = 0.f;
#pragma unroll
            for (int i = 0; i < 8; ++i) { p[i] = __expf(e[i] - m_new); ps += p[i]; }
            ps += __shfl_xor(ps, 1);
            ps += __shfl_xor(ps, 2);
            ps += __shfl_xor(ps, 4);
            if ((tid & 7) == 0) {
                const float f = __expf(m_old - m_new);
                fac_s[q] = f;
                l_s[q]   = l_s[q] * f + ps;
                m_s[q]   = m_new;
            }
            bf16x8 pb;
#pragma unroll
            for (int i = 0; i < 8; ++i) pb[i] = (bf16_t)p[i];
            *(bf16x8*)(&p_tile[q][kc]) = pb;
        }
        __syncthreads();
        // ---- ph3: rescale accumulator + P@V (V from transposed layout)
        float fr0[4], fr1[4];
#pragma unroll
        for (int rr = 0; rr < 4; ++rr) {
            fr0[rr] = fac_s[g * 4 + rr];
            fr1[rr] = fac_s[16 + g * 4 + rr];
        }
#pragma unroll
        for (int nt = 0; nt < 4; ++nt)
#pragma unroll
            for (int rr = 0; rr < 4; ++rr) {
                oacc[0][nt][rr] *= fr0[rr];
                oacc[1][nt][rr] *= fr1[rr];
            }
#pragma unroll
        for (int ks = 0; ks < 2; ++ks) {
            bf16x8 pa0 = *(const bf16x8*)(&p_tile[r][ks * 32 + g * 8]);
            bf16x8 pa1 = *(const bf16x8*)(&p_tile[16 + r][ks * 32 + g * 8]);
#pragma unroll
            for (int nt = 0; nt < 4; ++nt) {
                bf16x8 vb = *(const bf16x8*)(Vtp + (size_t)(w * 64 + nt * 16 + r) * S_LEN
                                                  + k0 + ks * 32 + g * 8);
                oacc[0][nt] = mfma16(pa0, vb, oacc[0][nt]);
                oacc[1][nt] = mfma16(pa1, vb, oacc[1][nt]);
            }
        }
        __syncthreads();
    }
    // ---- finalize
    float li0[4], li1[4];
#pragma unroll
    for (int rr = 0; rr < 4; ++rr) {
        li0[rr] = 1.f / l_s[g * 4 + rr];
        li1[rr] = 1.f / l_s[16 + g * 4 + rr];
    }
    bf16_t* Op = AO + ((size_t)b * S_LEN + q0) * D_HID;
#pragma unroll
    for (int nt = 0; nt < 4; ++nt)
#pragma unroll
        for (int rr = 0; rr < 4; ++rr) {
            Op[(size_t)(g * 4 + rr) * D_HID + w * 64 + nt * 16 + r]      = (bf16_t)(oacc[0][nt][rr] * li0[rr]);
            Op[(size_t)(16 + g * 4 + rr) * D_HID + w * 64 + nt * 16 + r] = (bf16_t)(oacc[1][nt][rr] * li1[rr]);
        }
}

// ---------------------------------------------------------------------------
extern "C" void kernel_launch(void* const* d_in, const int* in_sizes, int n_in,
                              void* d_out, int out_size, void* d_ws, size_t ws_size,
                              hipStream_t stream) {
    const float* x_in = (const float*)d_in[0];
    const int*   mask = (const int*)d_in[1];
    const float* btab = (const float*)d_in[2];
    const float* ln_g = (const float*)d_in[3];
    const float* ln_b = (const float*)d_in[4];
    const float* wq = (const float*)d_in[5];
    const float* bq = (const float*)d_in[6];
    const float* wk = (const float*)d_in[7];
    const float* bk = (const float*)d_in[8];
    const float* wv = (const float*)d_in[9];
    const float* bv = (const float*)d_in[10];
    const float* wo = (const float*)d_in[11];
    const float* bo = (const float*)d_in[12];
    const float* cg = (const float*)d_in[13];
    const float* cb = (const float*)d_in[14];
    const float* w1 = (const float*)d_in[15];
    const float* b1 = (const float*)d_in[16];
    const float* w2 = (const float*)d_in[17];
    const float* b2 = (const float*)d_in[18];
    float* out = (float*)d_out;

    // Workspace layout (~137 MB), regions reused across stage lifetimes.
    char* p = (char*)d_ws;
    const size_t F32SZ  = (size_t)M_ROWS * D_HID * sizeof(float);   // 33.5 MB
    const size_t BF16SZ = (size_t)M_ROWS * D_HID * sizeof(bf16_t);  // 16.8 MB
    float*  H  = (float*)p;  p += F32SZ;
    float*  X  = (float*)p;  p += F32SZ;
    bf16_t* Hb = (bf16_t*)p; p += BF16SZ;   // later: AO
    bf16_t* Qb = (bf16_t*)p; p += BF16SZ;   // later: Cb
    bf16_t* Kb = (bf16_t*)p;                // T (f32) spans Kb+Vt; T1b reuses Kb
    float*  T  = (float*)Kb;
    bf16_t* T1b = Kb;
    p += BF16SZ;
    bf16_t* Vt = (bf16_t*)p; p += BF16SZ;   // transposed V [b][d][s]
    bf16_t* Wqkv = (bf16_t*)p; p += (size_t)N_L * 768 * 256 * sizeof(bf16_t);  // packed
    bf16_t* Wrest = (bf16_t*)p;             // Wo,W1,W2: 3 * L * 65536 bf16
    bf16_t* AO = Hb;
    bf16_t* Cb = Qb;

    const int WELEMS = N_L * D_HID * D_HID;   // 196608 per weight tensor
    // QKV packed: layer stride 3*65536, tensor offset t*65536
    transpose_w<<<dim3(WELEMS / 256), dim3(256), 0, stream>>>(wq, Wqkv + 0 * 65536, 3 * 65536);
    transpose_w<<<dim3(WELEMS / 256), dim3(256), 0, stream>>>(wk, Wqkv + 1 * 65536, 3 * 65536);
    transpose_w<<<dim3(WELEMS / 256), dim3(256), 0, stream>>>(wv, Wqkv + 2 * 65536, 3 * 65536);
    transpose_w<<<dim3(WELEMS / 256), dim3(256), 0, stream>>>(wo, Wrest + (size_t)0 * WELEMS, 65536);
    transpose_w<<<dim3(WELEMS / 256), dim3(256), 0, stream>>>(w1, Wrest + (size_t)1 * WELEMS, 65536);
    transpose_w<<<dim3(WELEMS / 256), dim3(256), 0, stream>>>(w2, Wrest + (size_t)2 * WELEMS, 65536);

    const dim3 gblk(256, 1, 1);
    const dim3 grid_qkv(M_ROWS / 128, 6, 1);
    const dim3 grid_one(M_ROWS / 128, 2, 1);

    for (int j = 0; j < N_L; ++j) {
        const bf16_t* WQKVj = Wqkv + (size_t)j * 3 * 65536;
        const bf16_t* WOt = Wrest + ((size_t)0 * N_L + j) * 65536;
        const bf16_t* W1t = Wrest + ((size_t)1 * N_L + j) * 65536;
        const bf16_t* W2t = Wrest + ((size_t)2 * N_L + j) * 65536;

        ln_fwd<<<dim3(M_ROWS / 4), gblk, 0, stream>>>(j == 0 ? x_in : X,
                                                      ln_g + j * D_HID, ln_b + j * D_HID, H, Hb);
        gemm_qkv<<<grid_qkv, gblk, 0, stream>>>(Hb, WQKVj, bq + j * D_HID, bk + j * D_HID,
                                                bv + j * D_HID, Qb, Kb, Vt);
        attn_fwd<<<dim3(N_B, S_LEN / 32), gblk, 0, stream>>>(Qb, Kb, Vt, btab, mask, AO);
        gemm_one<2><<<grid_one, gblk, 0, stream>>>(AO, WOt, bo + j * D_HID, T, nullptr);
        ln_res_ln<<<dim3(M_ROWS / 4), gblk, 0, stream>>>(T, H, ln_g + j * D_HID, ln_b + j * D_HID,
                                                         cg + j * D_HID, cb + j * D_HID, X, Cb);
        gemm_one<1><<<grid_one, gblk, 0, stream>>>(Cb, W1t, b1 + j * D_HID, T1b, nullptr);
        gemm_one<3><<<grid_one, gblk, 0, stream>>>(T1b, W2t, b2 + j * D_HID,
                                                   (j == N_L - 1) ? (void*)out : (void*)X, X);
    }
}